// Round 14
// baseline (256.556 us; speedup 1.0000x reference)
//
#include <hip/hip_runtime.h>
#include <hip/hip_bf16.h>
#include <hip/hip_fp16.h>

#define EPS 1e-5f

constexpr int NN = 50000;   // nodes
constexpr int NE = 800000;  // edges

typedef __attribute__((ext_vector_type(8))) __bf16 bf16x8;
typedef __attribute__((ext_vector_type(4))) float f32x4;

// ---------------- utility ----------------
// NOTE: do NOT use hipMemsetAsync for small fills inside the captured graph:
// rocclr fillBufferAligned ran 40.5us for 195KB (r13 profile). This kernel: ~2us.
__global__ void memset_i32(int* p, int n) {
  int i = blockIdx.x * blockDim.x + threadIdx.x;
  if (i < n) p[i] = 0;
}

// ---------------- degree + slot capture ----------------
// pos8[i] = this edge's arrival rank at its dst (max deg ~40 << 255)
__global__ void deg_pos(const int* __restrict__ dst, int* __restrict__ degi,
                        unsigned char* __restrict__ pos8, int n) {
  int i = blockIdx.x * blockDim.x + threadIdx.x;
  if (i < n) pos8[i] = (unsigned char)atomicAdd(&degi[dst[i]], 1);
}

// ---------------- scan (row_ptr build) ----------------
__global__ __launch_bounds__(1024) void scan1(const int* __restrict__ cnt,
                                              int* __restrict__ incl,
                                              int* __restrict__ bsum, int n) {
  __shared__ int s[1024];
  int tid = threadIdx.x;
  int i = blockIdx.x * 1024 + tid;
  int v = (i < n) ? cnt[i] : 0;
  s[tid] = v;
  __syncthreads();
  for (int off = 1; off < 1024; off <<= 1) {
    int t = (tid >= off) ? s[tid - off] : 0;
    __syncthreads();
    s[tid] += t;
    __syncthreads();
  }
  if (i < n) incl[i] = s[tid];
  if (tid == 1023) bsum[blockIdx.x] = s[1023];
}

__global__ void scan2(int* __restrict__ bsum, int nb) {
  int lane = threadIdx.x;  // single wave of 64
  int v = (lane < nb) ? bsum[lane] : 0;
  int orig = v;
  for (int off = 1; off < 64; off <<= 1) {
    int t = __shfl_up(v, off, 64);
    if (lane >= off) v += t;
  }
  if (lane < nb) bsum[lane] = v - orig;  // exclusive block offset
}

// scan3 + fused dinv compute (atomic-free fill needs no cursor)
__global__ __launch_bounds__(1024) void scan3(const int* __restrict__ cnt,
                                              const int* __restrict__ incl,
                                              const int* __restrict__ bsum,
                                              int* __restrict__ rp,
                                              float* __restrict__ dinv, int n) {
  int tid = threadIdx.x;
  int i = blockIdx.x * 1024 + tid;
  if (i < n) {
    rp[i + 1] = incl[i] + bsum[blockIdx.x];
    dinv[i] = rsqrtf((float)(cnt[i] + 1));  // +1 self loop
  }
  if (i == 0) rp[0] = 0;
}

// atomic-free fill: position known from deg_pos capture
__global__ void fill_kernel(const int* __restrict__ src, const int* __restrict__ dst,
                            const int* __restrict__ rp,
                            const unsigned char* __restrict__ pos8,
                            unsigned short* __restrict__ col, int n) {
  int i = blockIdx.x * blockDim.x + threadIdx.x;
  if (i < n) col[rp[dst[i]] + pos8[i]] = (unsigned short)src[i];
}

// ---------------- fused: weight transpose+split (4 layers) + x prescale->fp16 ----
__device__ __forceinline__ void wsplit_one(const float* W, __bf16* th, __bf16* tl,
                                           int j, int K, int N) {
  int k = j / N, n = j - k * N;
  float v = W[j];
  __bf16 h = (__bf16)v;
  th[(size_t)n * K + k] = h;
  tl[(size_t)n * K + k] = (__bf16)(v - (float)h);
}

__global__ void wsplit_scale(const float* __restrict__ W1, __bf16* t1h, __bf16* t1l,
                             const float* __restrict__ W2, __bf16* t2h, __bf16* t2l,
                             const float* __restrict__ W3, __bf16* t3h, __bf16* t3l,
                             const float* __restrict__ W4, __bf16* t4h, __bf16* t4l,
                             const float* __restrict__ x, const float* __restrict__ dinv,
                             __half* __restrict__ Xh) {
  int i = blockIdx.x * blockDim.x + threadIdx.x;
  if (i < 32768) { wsplit_one(W1, t1h, t1l, i, 128, 256); return; }
  if (i < 65536) { wsplit_one(W2, t2h, t2l, i - 32768, 256, 128); return; }
  if (i < 73728) { wsplit_one(W3, t3h, t3l, i - 65536, 128, 64); return; }
  if (i < 74112) { wsplit_one(W4, t4h, t4l, i - 73728, 64, 6); return; }
  int k = i - 74112;  // float4 index over x[NN][128]
  if (k >= NN * 32) return;
  int v = k >> 5, f = (k & 31) * 4;
  float4 t = ((const float4*)x)[k];
  float s = dinv[v];
  __half2* d = (__half2*)(Xh + (size_t)v * 128 + f);
  d[0] = __floats2half2_rn(t.x * s, t.y * s);
  d[1] = __floats2half2_rn(t.z * s, t.w * s);
}

// ---------------- propagation (pull over CSR), fp16 gather planes, D=8 ----------------
// One wave per node; input rows fp16, prescaled by dinv[src]. 8 gathers in
// flight per wave; f32 accumulate. D=8 @ 8 waves/SIMD is the proven operating
// point (D=16 under launch_bounds(256,8) spills: r12, WRITE 25->176MB).
// EPI 0 = *dinv[v]; 1 = *dinv[v]+bias+BN+ReLU. Output: bf16 hi/lo planes.
template <int F, int EPI>
__global__ __launch_bounds__(256, 8) void prop_half(
    const __half* __restrict__ in, const int* __restrict__ rp,
    const unsigned short* __restrict__ col,
    const float* __restrict__ dinv, const float* __restrict__ bias,
    const float* __restrict__ gam, const float* __restrict__ bet,
    const float* __restrict__ mean, const float* __restrict__ var,
    __bf16* __restrict__ out_hi, __bf16* __restrict__ out_lo, int nnodes) {
  int tid = threadIdx.x;
  int wid = tid >> 6, lane = tid & 63;
  constexpr int VEC = F / 64;  // 2 for F=128, 1 for F=64
  int v = blockIdx.x * 4 + wid;
  if (v >= nnodes) return;
  int e0 = rp[v], e1 = rp[v + 1];
  float acc[VEC];
  if constexpr (VEC == 2) {
    float2 f = __half22float2(*(const __half2*)(in + (size_t)v * F + lane * 2));
    acc[0] = f.x; acc[1] = f.y;
  } else {
    acc[0] = __half2float(in[(size_t)v * F + lane]);
  }
  int e1m1 = e1 - 1;
  constexpr int D = 8;
  for (int e = e0; e < e1; e += D) {
    bool full = (e + D <= e1);
    int ss[D];
    if (full) {
#pragma unroll
      for (int u = 0; u < D; u++) ss[u] = col[e + u];
      if constexpr (VEC == 2) {
        __half2 hv[D];
#pragma unroll
        for (int u = 0; u < D; u++)
          hv[u] = *(const __half2*)(in + (size_t)ss[u] * F + lane * 2);
#pragma unroll
        for (int u = 0; u < D; u++) {
          float2 f = __half22float2(hv[u]);
          acc[0] += f.x;
          acc[1] += f.y;
        }
      } else {
        __half hv[D];
#pragma unroll
        for (int u = 0; u < D; u++) hv[u] = in[(size_t)ss[u] * F + lane];
#pragma unroll
        for (int u = 0; u < D; u++) acc[0] += __half2float(hv[u]);
      }
    } else {
      float w[D];
#pragma unroll
      for (int u = 0; u < D; u++) {
        int ei = e + u;
        ss[u] = col[ei < e1m1 ? ei : e1m1];
        w[u] = (ei < e1) ? 1.f : 0.f;
      }
      if constexpr (VEC == 2) {
        __half2 hv[D];
#pragma unroll
        for (int u = 0; u < D; u++)
          hv[u] = *(const __half2*)(in + (size_t)ss[u] * F + lane * 2);
#pragma unroll
        for (int u = 0; u < D; u++) {
          float2 f = __half22float2(hv[u]);
          acc[0] = fmaf(f.x, w[u], acc[0]);
          acc[1] = fmaf(f.y, w[u], acc[1]);
        }
      } else {
        __half hv[D];
#pragma unroll
        for (int u = 0; u < D; u++) hv[u] = in[(size_t)ss[u] * F + lane];
#pragma unroll
        for (int u = 0; u < D; u++) acc[0] = fmaf(__half2float(hv[u]), w[u], acc[0]);
      }
    }
  }
  float dv = dinv[v];
#pragma unroll
  for (int j = 0; j < VEC; j++) {
    int f = lane * VEC + j;
    float t = acc[j] * dv;
    if constexpr (EPI >= 1) {
      t += bias[f];
      t = (t - mean[f]) * rsqrtf(var[f] + EPS) * gam[f] + bet[f];
      t = fmaxf(t, 0.f);
    }
    __bf16 h = (__bf16)t;
    out_hi[(size_t)v * F + f] = h;
    out_lo[(size_t)v * F + f] = (__bf16)(t - (float)h);
  }
}

// ---------------- final prop (F=6), f32 input ----------------
__global__ __launch_bounds__(256, 8) void prop_small(
    const float* __restrict__ in, const int* __restrict__ rp,
    const unsigned short* __restrict__ col,
    const float* __restrict__ dinv, const float* __restrict__ bias,
    float* __restrict__ out, int nnodes) {
  constexpr int F = 6;
  int tid = threadIdx.x;
  int wid = tid >> 6, lane = tid & 63;
  int g = lane >> 3, f = lane & 7;
  int v = (blockIdx.x * 4 + wid) * 8 + g;
  if (v >= nnodes || f >= F) return;
  int e0 = rp[v], e1 = rp[v + 1];
  float acc = in[(size_t)v * F + f];
  int e1m1 = e1 - 1;
  constexpr int D = 8;
  for (int e = e0; e < e1; e += D) {
    int ss[D];
    float w[D];
#pragma unroll
    for (int u = 0; u < D; u++) {
      int ei = e + u;
      ss[u] = col[ei < e1m1 ? ei : e1m1];
      w[u] = (ei < e1) ? 1.0f : 0.0f;
    }
#pragma unroll
    for (int u = 0; u < D; u++) acc = fmaf(in[(size_t)ss[u] * F + f], w[u], acc);
  }
  out[(size_t)v * F + f] = acc * dinv[v] + bias[f];
}

// ---------------- MFMA GEMM (bf16 split-3), 128xBN tile, 4 waves ----------------
// A as hi/lo planes [M][K]; B as transposed hi/lo planes [N][K].
// EPI 0: +bias, BN, ReLU -> bf16 hi/lo planes.
// EPI 1: *dinv[row] -> fp16 plane (next prop's gather input).
// EPI 2: *dinv[row] -> f32 linear (final small layer).
template <int BN, int EPI>
__global__ __launch_bounds__(256, 4) void mfma_gemm(
    const __bf16* __restrict__ Ahi, const __bf16* __restrict__ Alo,
    const __bf16* __restrict__ Bhi, const __bf16* __restrict__ Blo,
    const float* __restrict__ bias, const float* __restrict__ gam,
    const float* __restrict__ bet, const float* __restrict__ mean,
    const float* __restrict__ var, const float* __restrict__ dinv,
    float* __restrict__ Cf, __half* __restrict__ Ch,
    __bf16* __restrict__ Chi, __bf16* __restrict__ Clo,
    int M, int K, int N) {
  constexpr int BM = 128, BK = 32, NB = BN / 16;
  // +8 bf16 pad (16 B): row stride 80 B spreads b128 frag reads across all 32 banks
  __shared__ __bf16 Ah[BM][BK + 8], Al[BM][BK + 8];
  __shared__ __bf16 Bh[BN][BK + 8], Bl[BN][BK + 8];
  int tid = threadIdx.x;
  int wid = tid >> 6, lane = tid & 63;
  int lr = lane & 15, lg = lane >> 4;
  int bm = blockIdx.x * BM, bn = blockIdx.y * BN;
  f32x4 acc[2][NB] = {};
  for (int k0 = 0; k0 < K; k0 += BK) {
#pragma unroll
    for (int c = 0; c < 2; c++) {  // A tile: 128 rows x 32 bf16, 16B chunks
      int idx = tid + c * 256;
      int r = idx >> 2, s = idx & 3;
      int rg = bm + r;
      uint4 vh = {0, 0, 0, 0}, vl = {0, 0, 0, 0};
      if (rg < M) {
        size_t go = (size_t)rg * K + k0 + s * 8;
        vh = *reinterpret_cast<const uint4*>(Ahi + go);
        vl = *reinterpret_cast<const uint4*>(Alo + go);
      }
      *reinterpret_cast<uint4*>(&Ah[r][s * 8]) = vh;
      *reinterpret_cast<uint4*>(&Al[r][s * 8]) = vl;
    }
#pragma unroll
    for (int c = 0; c < (BN * 4 + 255) / 256; c++) {  // B tile: BN rows x 32 bf16
      int idx = tid + c * 256;
      if (idx < BN * 4) {
        int r = idx >> 2, s = idx & 3;
        int rg = bn + r;
        uint4 vh = {0, 0, 0, 0}, vl = {0, 0, 0, 0};
        if (rg < N) {
          size_t go = (size_t)rg * K + k0 + s * 8;
          vh = *reinterpret_cast<const uint4*>(Bhi + go);
          vl = *reinterpret_cast<const uint4*>(Blo + go);
        }
        *reinterpret_cast<uint4*>(&Bh[r][s * 8]) = vh;
        *reinterpret_cast<uint4*>(&Bl[r][s * 8]) = vl;
      }
    }
    __syncthreads();
    int ar = wid * 32 + lr;
    bf16x8 ah0 = *reinterpret_cast<const bf16x8*>(&Ah[ar][lg * 8]);
    bf16x8 ah1 = *reinterpret_cast<const bf16x8*>(&Ah[ar + 16][lg * 8]);
    bf16x8 al0 = *reinterpret_cast<const bf16x8*>(&Al[ar][lg * 8]);
    bf16x8 al1 = *reinterpret_cast<const bf16x8*>(&Al[ar + 16][lg * 8]);
#pragma unroll
    for (int n = 0; n < NB; n++) {
      bf16x8 bh = *reinterpret_cast<const bf16x8*>(&Bh[n * 16 + lr][lg * 8]);
      bf16x8 bl = *reinterpret_cast<const bf16x8*>(&Bl[n * 16 + lr][lg * 8]);
      acc[0][n] = __builtin_amdgcn_mfma_f32_16x16x32_bf16(ah0, bh, acc[0][n], 0, 0, 0);
      acc[1][n] = __builtin_amdgcn_mfma_f32_16x16x32_bf16(ah1, bh, acc[1][n], 0, 0, 0);
      acc[0][n] = __builtin_amdgcn_mfma_f32_16x16x32_bf16(ah0, bl, acc[0][n], 0, 0, 0);
      acc[1][n] = __builtin_amdgcn_mfma_f32_16x16x32_bf16(ah1, bl, acc[1][n], 0, 0, 0);
      acc[0][n] = __builtin_amdgcn_mfma_f32_16x16x32_bf16(al0, bh, acc[0][n], 0, 0, 0);
      acc[1][n] = __builtin_amdgcn_mfma_f32_16x16x32_bf16(al1, bh, acc[1][n], 0, 0, 0);
    }
    __syncthreads();
  }
  // epilogue: C/D layout col=lane&15, row=(lane>>4)*4+reg (m89-verified)
#pragma unroll
  for (int m = 0; m < 2; m++) {
    int row0 = bm + wid * 32 + m * 16 + lg * 4;
#pragma unroll
    for (int n = 0; n < NB; n++) {
      int colg = bn + n * 16 + lr;
#pragma unroll
      for (int r = 0; r < 4; r++) {
        int row = row0 + r;
        if (row >= M) continue;
        float t = acc[m][n][r];
        if constexpr (EPI == 0) {
          t += bias[colg];
          t = (t - mean[colg]) * rsqrtf(var[colg] + EPS) * gam[colg] + bet[colg];
          t = fmaxf(t, 0.f);
          __bf16 h = (__bf16)t;
          Chi[(size_t)row * N + colg] = h;
          Clo[(size_t)row * N + colg] = (__bf16)(t - (float)h);
        } else if constexpr (EPI == 1) {
          Ch[(size_t)row * N + colg] = __float2half(t * dinv[row]);
        } else {
          if (colg < N) Cf[(size_t)row * N + colg] = t * dinv[row];
        }
      }
    }
  }
}

// ---------------- launch ----------------
extern "C" void kernel_launch(void* const* d_in, const int* in_sizes, int n_in,
                              void* d_out, int out_size, void* d_ws, size_t ws_size,
                              hipStream_t stream) {
  const float* x = (const float*)d_in[0];
  const int* ei = (const int*)d_in[1];
  const int* esrc = ei;
  const int* edst = ei + NE;
  const float* W1 = (const float*)d_in[2];  const float* b1 = (const float*)d_in[3];
  const float* g1 = (const float*)d_in[4];  const float* be1 = (const float*)d_in[5];
  const float* m1 = (const float*)d_in[6];  const float* v1 = (const float*)d_in[7];
  const float* W2 = (const float*)d_in[8];  const float* b2 = (const float*)d_in[9];
  const float* g2 = (const float*)d_in[10]; const float* be2 = (const float*)d_in[11];
  const float* m2 = (const float*)d_in[12]; const float* v2 = (const float*)d_in[13];
  const float* W3 = (const float*)d_in[14]; const float* b3 = (const float*)d_in[15];
  const float* g3 = (const float*)d_in[16]; const float* be3 = (const float*)d_in[17];
  const float* m3 = (const float*)d_in[18]; const float* v3 = (const float*)d_in[19];
  const float* W4 = (const float*)d_in[20]; const float* b4 = (const float*)d_in[21];
  float* out = (float*)d_out;

  // workspace layout
  char* base = (char*)d_ws;
  size_t off = 0;
  auto alloc = [&](size_t bytes) {
    void* p = base + off;
    off = (off + bytes + 255) & ~(size_t)255;
    return p;
  };
  __half* Xh = (__half*)alloc((size_t)NN * 128 * 2);      // fp16 gather plane (<=128 cols)
  float* F1 = (float*)alloc((size_t)NN * 6 * 4);          // f32 pre-final activations
  __bf16* PAh = (__bf16*)alloc((size_t)NN * 128 * 2);     // A planes (<=128 cols)
  __bf16* PAl = (__bf16*)alloc((size_t)NN * 128 * 2);
  __bf16* PHh = (__bf16*)alloc((size_t)NN * 256 * 2);     // h planes (<=256 cols)
  __bf16* PHl = (__bf16*)alloc((size_t)NN * 256 * 2);
  __bf16* Wt1h = (__bf16*)alloc(128 * 256 * 2); __bf16* Wt1l = (__bf16*)alloc(128 * 256 * 2);
  __bf16* Wt2h = (__bf16*)alloc(256 * 128 * 2); __bf16* Wt2l = (__bf16*)alloc(256 * 128 * 2);
  __bf16* Wt3h = (__bf16*)alloc(128 * 64 * 2);  __bf16* Wt3l = (__bf16*)alloc(128 * 64 * 2);
  __bf16* Wt4h = (__bf16*)alloc(64 * 6 * 2);    __bf16* Wt4l = (__bf16*)alloc(64 * 6 * 2);
  int* degi = (int*)alloc((size_t)NN * 4);
  float* dinv = (float*)alloc((size_t)NN * 4);
  int* rp = (int*)alloc((size_t)(NN + 1) * 4);
  int* incl = (int*)alloc((size_t)NN * 4);
  int* bsum = (int*)alloc(64 * 4);
  unsigned short* col = (unsigned short*)alloc((size_t)NE * 2);
  unsigned char* pos8 = (unsigned char*)alloc((size_t)NE);

  const int nBlkN = (NN + 255) / 256;
  const int nBlkE = (NE + 255) / 256;
  const int nBlkScan = (NN + 1023) / 1024;  // 49
  const int gM = (NN + 127) / 128;          // 391
  const int gP = (NN + 3) / 4;              // 12500

  // degree (+slot capture) + CSR (atomic-free fill)
  memset_i32<<<nBlkN, 256, 0, stream>>>(degi, NN);
  deg_pos<<<nBlkE, 256, 0, stream>>>(edst, degi, pos8, NE);
  scan1<<<nBlkScan, 1024, 0, stream>>>(degi, incl, bsum, NN);
  scan2<<<1, 64, 0, stream>>>(bsum, nBlkScan);
  scan3<<<nBlkScan, 1024, 0, stream>>>(degi, incl, bsum, rp, dinv, NN);
  fill_kernel<<<nBlkE, 256, 0, stream>>>(esrc, edst, rp, pos8, col, NE);

  // fused weight split + x prescale->fp16 (74112 + NN*32 items)
  wsplit_scale<<<(74112 + NN * 32 + 255) / 256, 256, 0, stream>>>(
      W1, Wt1h, Wt1l, W2, Wt2h, Wt2l, W3, Wt3h, Wt3l, W4, Wt4h, Wt4l, x, dinv, Xh);

  // ---- layer 1: prop(128), GEMM1(+b1,BN1,ReLU -> bf16 planes) ----
  prop_half<128, 0><<<gP, 256, 0, stream>>>(Xh, rp, col, dinv, nullptr, nullptr, nullptr,
                                            nullptr, nullptr, PAh, PAl, NN);
  {
    dim3 g(gM, 2);
    mfma_gemm<128, 0><<<g, 256, 0, stream>>>(PAh, PAl, Wt1h, Wt1l, b1, g1, be1, m1, v1,
                                             nullptr, nullptr, nullptr, PHh, PHl,
                                             NN, 128, 256);
  }
  // ---- layer 2: GEMM2(*dinv -> fp16), prop(128, +b2,BN2,ReLU -> bf16 planes) ----
  {
    dim3 g(gM, 1);
    mfma_gemm<128, 1><<<g, 256, 0, stream>>>(PHh, PHl, Wt2h, Wt2l, nullptr, nullptr,
                                             nullptr, nullptr, nullptr, dinv,
                                             nullptr, Xh, nullptr, nullptr, NN, 256, 128);
  }
  prop_half<128, 1><<<gP, 256, 0, stream>>>(Xh, rp, col, dinv, b2, g2, be2, m2, v2,
                                            PAh, PAl, NN);
  // ---- layer 3: GEMM3(*dinv -> fp16), prop(64, +b3,BN3,ReLU -> bf16 planes) ----
  {
    dim3 g(gM, 1);
    mfma_gemm<64, 1><<<g, 256, 0, stream>>>(PAh, PAl, Wt3h, Wt3l, nullptr, nullptr,
                                            nullptr, nullptr, nullptr, dinv,
                                            nullptr, Xh, nullptr, nullptr, NN, 128, 64);
  }
  prop_half<64, 1><<<gP, 256, 0, stream>>>(Xh, rp, col, dinv, b3, g3, be3, m3, v3,
                                           PHh, PHl, NN);
  // ---- layer 4: GEMM4(*dinv -> f32, N=6), final prop (+b4) ----
  {
    dim3 g(gM, 1);
    mfma_gemm<16, 2><<<g, 256, 0, stream>>>(PHh, PHl, Wt4h, Wt4l, nullptr, nullptr,
                                            nullptr, nullptr, nullptr, dinv,
                                            F1, nullptr, nullptr, nullptr, NN, 64, 6);
  }
  prop_small<<<(NN + 31) / 32, 256, 0, stream>>>(F1, rp, col, dinv, b4, out, NN);
}

// Round 15
// 237.556 us; speedup vs baseline: 1.0800x; 1.0800x over previous
//
#include <hip/hip_runtime.h>
#include <hip/hip_bf16.h>
#include <hip/hip_fp16.h>

#define EPS 1e-5f

constexpr int NN = 50000;   // nodes
constexpr int NE = 800000;  // edges

typedef __attribute__((ext_vector_type(8))) _Float16 f16x8;
typedef __attribute__((ext_vector_type(4))) float f32x4;

// ---------------- utility ----------------
__global__ void memset_i32(int* p, int n) {
  int i = blockIdx.x * blockDim.x + threadIdx.x;
  if (i < n) p[i] = 0;
}

// ---------------- degree + slot capture ----------------
// pos8[i] = this edge's arrival rank at its dst (max deg ~40 << 255)
__global__ void deg_pos(const int* __restrict__ dst, int* __restrict__ degi,
                        unsigned char* __restrict__ pos8, int n) {
  int i = blockIdx.x * blockDim.x + threadIdx.x;
  if (i < n) pos8[i] = (unsigned char)atomicAdd(&degi[dst[i]], 1);
}

// ---------------- scan (row_ptr build) ----------------
__global__ __launch_bounds__(1024) void scan1(const int* __restrict__ cnt,
                                              int* __restrict__ incl,
                                              int* __restrict__ bsum, int n) {
  __shared__ int s[1024];
  int tid = threadIdx.x;
  int i = blockIdx.x * 1024 + tid;
  int v = (i < n) ? cnt[i] : 0;
  s[tid] = v;
  __syncthreads();
  for (int off = 1; off < 1024; off <<= 1) {
    int t = (tid >= off) ? s[tid - off] : 0;
    __syncthreads();
    s[tid] += t;
    __syncthreads();
  }
  if (i < n) incl[i] = s[tid];
  if (tid == 1023) bsum[blockIdx.x] = s[1023];
}

__global__ void scan2(int* __restrict__ bsum, int nb) {
  int lane = threadIdx.x;  // single wave of 64
  int v = (lane < nb) ? bsum[lane] : 0;
  int orig = v;
  for (int off = 1; off < 64; off <<= 1) {
    int t = __shfl_up(v, off, 64);
    if (lane >= off) v += t;
  }
  if (lane < nb) bsum[lane] = v - orig;  // exclusive block offset
}

// scan3 + fused dinv compute
__global__ __launch_bounds__(1024) void scan3(const int* __restrict__ cnt,
                                              const int* __restrict__ incl,
                                              const int* __restrict__ bsum,
                                              int* __restrict__ rp,
                                              float* __restrict__ dinv, int n) {
  int tid = threadIdx.x;
  int i = blockIdx.x * 1024 + tid;
  if (i < n) {
    rp[i + 1] = incl[i] + bsum[blockIdx.x];
    dinv[i] = rsqrtf((float)(cnt[i] + 1));  // +1 self loop
  }
  if (i == 0) rp[0] = 0;
}

// atomic-free fill: position known from deg_pos capture
__global__ void fill_kernel(const int* __restrict__ src, const int* __restrict__ dst,
                            const int* __restrict__ rp,
                            const unsigned char* __restrict__ pos8,
                            unsigned short* __restrict__ col, int n) {
  int i = blockIdx.x * blockDim.x + threadIdx.x;
  if (i < n) col[rp[dst[i]] + pos8[i]] = (unsigned short)src[i];
}

// ---------------- fused: weight transpose+split fp16 hi/lo + x prescale->fp16 ----
// b = bh + bl (each fp16) carries ~22 mantissa bits -> weights near-exact.
__device__ __forceinline__ void wsplit_one(const float* W, __half* th, __half* tl,
                                           int j, int K, int N) {
  int k = j / N, n = j - k * N;
  float v = W[j];
  __half h = __float2half(v);
  th[(size_t)n * K + k] = h;
  tl[(size_t)n * K + k] = __float2half(v - __half2float(h));
}

__global__ void wsplit_scale(const float* __restrict__ W1, __half* t1h, __half* t1l,
                             const float* __restrict__ W2, __half* t2h, __half* t2l,
                             const float* __restrict__ W3, __half* t3h, __half* t3l,
                             const float* __restrict__ W4, __half* t4h, __half* t4l,
                             const float* __restrict__ x, const float* __restrict__ dinv,
                             __half* __restrict__ Xh) {
  int i = blockIdx.x * blockDim.x + threadIdx.x;
  if (i < 32768) { wsplit_one(W1, t1h, t1l, i, 128, 256); return; }
  if (i < 65536) { wsplit_one(W2, t2h, t2l, i - 32768, 256, 128); return; }
  if (i < 73728) { wsplit_one(W3, t3h, t3l, i - 65536, 128, 64); return; }
  if (i < 74112) { wsplit_one(W4, t4h, t4l, i - 73728, 64, 6); return; }
  int k = i - 74112;  // float4 index over x[NN][128]
  if (k >= NN * 32) return;
  int v = k >> 5, f = (k & 31) * 4;
  float4 t = ((const float4*)x)[k];
  float s = dinv[v];
  __half2* d = (__half2*)(Xh + (size_t)v * 128 + f);
  d[0] = __floats2half2_rn(t.x * s, t.y * s);
  d[1] = __floats2half2_rn(t.z * s, t.w * s);
}

// ---------------- propagation (pull over CSR), fp16 gather planes, D=8 ----------------
// One wave per node; input rows fp16, prescaled by dinv[src]. 8 gathers in
// flight per wave; f32 accumulate. D=8 @ 8 waves/SIMD is the proven operating
// point (D=16 under launch_bounds(256,8) spills: r12, WRITE 25->176MB).
// EPI 0 = *dinv[v]; 1 = *dinv[v]+bias+BN+ReLU. Output: single fp16 plane.
template <int F, int EPI>
__global__ __launch_bounds__(256, 8) void prop_half(
    const __half* __restrict__ in, const int* __restrict__ rp,
    const unsigned short* __restrict__ col,
    const float* __restrict__ dinv, const float* __restrict__ bias,
    const float* __restrict__ gam, const float* __restrict__ bet,
    const float* __restrict__ mean, const float* __restrict__ var,
    __half* __restrict__ out_h, int nnodes) {
  int tid = threadIdx.x;
  int wid = tid >> 6, lane = tid & 63;
  constexpr int VEC = F / 64;  // 2 for F=128, 1 for F=64
  int v = blockIdx.x * 4 + wid;
  if (v >= nnodes) return;
  int e0 = rp[v], e1 = rp[v + 1];
  float acc[VEC];
  if constexpr (VEC == 2) {
    float2 f = __half22float2(*(const __half2*)(in + (size_t)v * F + lane * 2));
    acc[0] = f.x; acc[1] = f.y;
  } else {
    acc[0] = __half2float(in[(size_t)v * F + lane]);
  }
  int e1m1 = e1 - 1;
  constexpr int D = 8;
  for (int e = e0; e < e1; e += D) {
    bool full = (e + D <= e1);
    int ss[D];
    if (full) {
#pragma unroll
      for (int u = 0; u < D; u++) ss[u] = col[e + u];
      if constexpr (VEC == 2) {
        __half2 hv[D];
#pragma unroll
        for (int u = 0; u < D; u++)
          hv[u] = *(const __half2*)(in + (size_t)ss[u] * F + lane * 2);
#pragma unroll
        for (int u = 0; u < D; u++) {
          float2 f = __half22float2(hv[u]);
          acc[0] += f.x;
          acc[1] += f.y;
        }
      } else {
        __half hv[D];
#pragma unroll
        for (int u = 0; u < D; u++) hv[u] = in[(size_t)ss[u] * F + lane];
#pragma unroll
        for (int u = 0; u < D; u++) acc[0] += __half2float(hv[u]);
      }
    } else {
      float w[D];
#pragma unroll
      for (int u = 0; u < D; u++) {
        int ei = e + u;
        ss[u] = col[ei < e1m1 ? ei : e1m1];
        w[u] = (ei < e1) ? 1.f : 0.f;
      }
      if constexpr (VEC == 2) {
        __half2 hv[D];
#pragma unroll
        for (int u = 0; u < D; u++)
          hv[u] = *(const __half2*)(in + (size_t)ss[u] * F + lane * 2);
#pragma unroll
        for (int u = 0; u < D; u++) {
          float2 f = __half22float2(hv[u]);
          acc[0] = fmaf(f.x, w[u], acc[0]);
          acc[1] = fmaf(f.y, w[u], acc[1]);
        }
      } else {
        __half hv[D];
#pragma unroll
        for (int u = 0; u < D; u++) hv[u] = in[(size_t)ss[u] * F + lane];
#pragma unroll
        for (int u = 0; u < D; u++) acc[0] = fmaf(__half2float(hv[u]), w[u], acc[0]);
      }
    }
  }
  float dv = dinv[v];
  float t0;
  {
    int f = lane * VEC;
    t0 = acc[0] * dv;
    if constexpr (EPI >= 1) {
      t0 += bias[f];
      t0 = (t0 - mean[f]) * rsqrtf(var[f] + EPS) * gam[f] + bet[f];
      t0 = fmaxf(t0, 0.f);
    }
  }
  if constexpr (VEC == 2) {
    int f = lane * 2 + 1;
    float t1 = acc[1] * dv;
    if constexpr (EPI >= 1) {
      t1 += bias[f];
      t1 = (t1 - mean[f]) * rsqrtf(var[f] + EPS) * gam[f] + bet[f];
      t1 = fmaxf(t1, 0.f);
    }
    *(__half2*)(out_h + (size_t)v * F + lane * 2) = __floats2half2_rn(t0, t1);
  } else {
    out_h[(size_t)v * F + lane] = __float2half(t0);
  }
}

// ---------------- final prop (F=6), f32 input ----------------
__global__ __launch_bounds__(256, 8) void prop_small(
    const float* __restrict__ in, const int* __restrict__ rp,
    const unsigned short* __restrict__ col,
    const float* __restrict__ dinv, const float* __restrict__ bias,
    float* __restrict__ out, int nnodes) {
  constexpr int F = 6;
  int tid = threadIdx.x;
  int wid = tid >> 6, lane = tid & 63;
  int g = lane >> 3, f = lane & 7;
  int v = (blockIdx.x * 4 + wid) * 8 + g;
  if (v >= nnodes || f >= F) return;
  int e0 = rp[v], e1 = rp[v + 1];
  float acc = in[(size_t)v * F + f];
  int e1m1 = e1 - 1;
  constexpr int D = 8;
  for (int e = e0; e < e1; e += D) {
    int ss[D];
    float w[D];
#pragma unroll
    for (int u = 0; u < D; u++) {
      int ei = e + u;
      ss[u] = col[ei < e1m1 ? ei : e1m1];
      w[u] = (ei < e1) ? 1.0f : 0.0f;
    }
#pragma unroll
    for (int u = 0; u < D; u++) acc = fmaf(in[(size_t)ss[u] * F + f], w[u], acc);
  }
  out[(size_t)v * F + f] = acc * dinv[v] + bias[f];
}

// ---------------- MFMA GEMM (fp16 split-2), 128xBN tile, 4 waves ----------------
// A single fp16 plane [M][K]; B = fp16 hi/lo transposed [N][K] (22-bit weights).
// 2 MFMA passes (a.bh + a.bl) vs bf16 split-3's 3 -> 2/3 MFMA, half A traffic.
// EPI 0: +bias, BN, ReLU -> fp16 plane. EPI 1: *dinv[row] -> fp16 plane.
// EPI 2: *dinv[row] -> f32 linear (final small layer).
template <int BN, int EPI>
__global__ __launch_bounds__(256, 4) void mfma_gemm(
    const __half* __restrict__ A,
    const __half* __restrict__ Bhi, const __half* __restrict__ Blo,
    const float* __restrict__ bias, const float* __restrict__ gam,
    const float* __restrict__ bet, const float* __restrict__ mean,
    const float* __restrict__ var, const float* __restrict__ dinv,
    float* __restrict__ Cf, __half* __restrict__ Ch,
    int M, int K, int N) {
  constexpr int BM = 128, BK = 32, NB = BN / 16;
  // +8 f16 pad (16 B): row stride 80 B spreads b128 frag reads across banks
  __shared__ __half Ah[BM][BK + 8];
  __shared__ __half Bh[BN][BK + 8], Bl[BN][BK + 8];
  int tid = threadIdx.x;
  int wid = tid >> 6, lane = tid & 63;
  int lr = lane & 15, lg = lane >> 4;
  int bm = blockIdx.x * BM, bn = blockIdx.y * BN;
  f32x4 acc[2][NB] = {};
  for (int k0 = 0; k0 < K; k0 += BK) {
#pragma unroll
    for (int c = 0; c < 2; c++) {  // A tile: 128 rows x 32 f16, 16B chunks
      int idx = tid + c * 256;
      int r = idx >> 2, s = idx & 3;
      int rg = bm + r;
      uint4 va = {0, 0, 0, 0};
      if (rg < M) va = *reinterpret_cast<const uint4*>(A + (size_t)rg * K + k0 + s * 8);
      *reinterpret_cast<uint4*>(&Ah[r][s * 8]) = va;
    }
#pragma unroll
    for (int c = 0; c < (BN * 4 + 255) / 256; c++) {  // B tile: BN rows x 32 f16 hi+lo
      int idx = tid + c * 256;
      if (idx < BN * 4) {
        int r = idx >> 2, s = idx & 3;
        int rg = bn + r;
        uint4 vh = {0, 0, 0, 0}, vl = {0, 0, 0, 0};
        if (rg < N) {
          size_t go = (size_t)rg * K + k0 + s * 8;
          vh = *reinterpret_cast<const uint4*>(Bhi + go);
          vl = *reinterpret_cast<const uint4*>(Blo + go);
        }
        *reinterpret_cast<uint4*>(&Bh[r][s * 8]) = vh;
        *reinterpret_cast<uint4*>(&Bl[r][s * 8]) = vl;
      }
    }
    __syncthreads();
    int ar = wid * 32 + lr;
    f16x8 a0 = *reinterpret_cast<const f16x8*>(&Ah[ar][lg * 8]);
    f16x8 a1 = *reinterpret_cast<const f16x8*>(&Ah[ar + 16][lg * 8]);
#pragma unroll
    for (int n = 0; n < NB; n++) {
      f16x8 bh = *reinterpret_cast<const f16x8*>(&Bh[n * 16 + lr][lg * 8]);
      f16x8 bl = *reinterpret_cast<const f16x8*>(&Bl[n * 16 + lr][lg * 8]);
      acc[0][n] = __builtin_amdgcn_mfma_f32_16x16x32_f16(a0, bh, acc[0][n], 0, 0, 0);
      acc[1][n] = __builtin_amdgcn_mfma_f32_16x16x32_f16(a1, bh, acc[1][n], 0, 0, 0);
      acc[0][n] = __builtin_amdgcn_mfma_f32_16x16x32_f16(a0, bl, acc[0][n], 0, 0, 0);
      acc[1][n] = __builtin_amdgcn_mfma_f32_16x16x32_f16(a1, bl, acc[1][n], 0, 0, 0);
    }
    __syncthreads();
  }
  // epilogue: C/D layout col=lane&15, row=(lane>>4)*4+reg (m89-verified)
#pragma unroll
  for (int m = 0; m < 2; m++) {
    int row0 = bm + wid * 32 + m * 16 + lg * 4;
#pragma unroll
    for (int n = 0; n < NB; n++) {
      int colg = bn + n * 16 + lr;
#pragma unroll
      for (int r = 0; r < 4; r++) {
        int row = row0 + r;
        if (row >= M || colg >= N) continue;
        float t = acc[m][n][r];
        if constexpr (EPI == 0) {
          t += bias[colg];
          t = (t - mean[colg]) * rsqrtf(var[colg] + EPS) * gam[colg] + bet[colg];
          t = fmaxf(t, 0.f);
          Ch[(size_t)row * N + colg] = __float2half(t);
        } else if constexpr (EPI == 1) {
          Ch[(size_t)row * N + colg] = __float2half(t * dinv[row]);
        } else {
          Cf[(size_t)row * N + colg] = t * dinv[row];
        }
      }
    }
  }
}

// ---------------- launch ----------------
extern "C" void kernel_launch(void* const* d_in, const int* in_sizes, int n_in,
                              void* d_out, int out_size, void* d_ws, size_t ws_size,
                              hipStream_t stream) {
  const float* x = (const float*)d_in[0];
  const int* ei = (const int*)d_in[1];
  const int* esrc = ei;
  const int* edst = ei + NE;
  const float* W1 = (const float*)d_in[2];  const float* b1 = (const float*)d_in[3];
  const float* g1 = (const float*)d_in[4];  const float* be1 = (const float*)d_in[5];
  const float* m1 = (const float*)d_in[6];  const float* v1 = (const float*)d_in[7];
  const float* W2 = (const float*)d_in[8];  const float* b2 = (const float*)d_in[9];
  const float* g2 = (const float*)d_in[10]; const float* be2 = (const float*)d_in[11];
  const float* m2 = (const float*)d_in[12]; const float* v2 = (const float*)d_in[13];
  const float* W3 = (const float*)d_in[14]; const float* b3 = (const float*)d_in[15];
  const float* g3 = (const float*)d_in[16]; const float* be3 = (const float*)d_in[17];
  const float* m3 = (const float*)d_in[18]; const float* v3 = (const float*)d_in[19];
  const float* W4 = (const float*)d_in[20]; const float* b4 = (const float*)d_in[21];
  float* out = (float*)d_out;

  // workspace layout
  char* base = (char*)d_ws;
  size_t off = 0;
  auto alloc = [&](size_t bytes) {
    void* p = base + off;
    off = (off + bytes + 255) & ~(size_t)255;
    return p;
  };
  __half* Xh = (__half*)alloc((size_t)NN * 128 * 2);   // fp16 gather plane (<=128 cols)
  __half* PA = (__half*)alloc((size_t)NN * 128 * 2);   // fp16 GEMM-A plane (<=128 cols)
  __half* H  = (__half*)alloc((size_t)NN * 256 * 2);   // fp16 wide plane (<=256 cols)
  float* F1 = (float*)alloc((size_t)NN * 6 * 4);       // f32 pre-final activations
  __half* Wt1h = (__half*)alloc(128 * 256 * 2); __half* Wt1l = (__half*)alloc(128 * 256 * 2);
  __half* Wt2h = (__half*)alloc(256 * 128 * 2); __half* Wt2l = (__half*)alloc(256 * 128 * 2);
  __half* Wt3h = (__half*)alloc(128 * 64 * 2);  __half* Wt3l = (__half*)alloc(128 * 64 * 2);
  __half* Wt4h = (__half*)alloc(64 * 6 * 2);    __half* Wt4l = (__half*)alloc(64 * 6 * 2);
  int* degi = (int*)alloc((size_t)NN * 4);
  float* dinv = (float*)alloc((size_t)NN * 4);
  int* rp = (int*)alloc((size_t)(NN + 1) * 4);
  int* incl = (int*)alloc((size_t)NN * 4);
  int* bsum = (int*)alloc(64 * 4);
  unsigned short* col = (unsigned short*)alloc((size_t)NE * 2);
  unsigned char* pos8 = (unsigned char*)alloc((size_t)NE);

  const int nBlkN = (NN + 255) / 256;
  const int nBlkE = (NE + 255) / 256;
  const int nBlkScan = (NN + 1023) / 1024;  // 49
  const int gM = (NN + 127) / 128;          // 391
  const int gP = (NN + 3) / 4;              // 12500

  // degree (+slot capture) + CSR (atomic-free fill)
  memset_i32<<<nBlkN, 256, 0, stream>>>(degi, NN);
  deg_pos<<<nBlkE, 256, 0, stream>>>(edst, degi, pos8, NE);
  scan1<<<nBlkScan, 1024, 0, stream>>>(degi, incl, bsum, NN);
  scan2<<<1, 64, 0, stream>>>(bsum, nBlkScan);
  scan3<<<nBlkScan, 1024, 0, stream>>>(degi, incl, bsum, rp, dinv, NN);
  fill_kernel<<<nBlkE, 256, 0, stream>>>(esrc, edst, rp, pos8, col, NE);

  // fused weight split (fp16 hi/lo) + x prescale->fp16
  wsplit_scale<<<(74112 + NN * 32 + 255) / 256, 256, 0, stream>>>(
      W1, Wt1h, Wt1l, W2, Wt2h, Wt2l, W3, Wt3h, Wt3l, W4, Wt4h, Wt4l, x, dinv, Xh);

  // ---- layer 1: prop(128) -> PA, GEMM1(+b1,BN1,ReLU) -> H[256] ----
  prop_half<128, 0><<<gP, 256, 0, stream>>>(Xh, rp, col, dinv, nullptr, nullptr, nullptr,
                                            nullptr, nullptr, PA, NN);
  {
    dim3 g(gM, 2);
    mfma_gemm<128, 0><<<g, 256, 0, stream>>>(PA, Wt1h, Wt1l, b1, g1, be1, m1, v1,
                                             nullptr, nullptr, H, NN, 128, 256);
  }
  // ---- layer 2: GEMM2(*dinv) -> Xh[128], prop(128,+b2,BN2,ReLU) -> PA ----
  {
    dim3 g(gM, 1);
    mfma_gemm<128, 1><<<g, 256, 0, stream>>>(H, Wt2h, Wt2l, nullptr, nullptr, nullptr,
                                             nullptr, nullptr, dinv, nullptr, Xh,
                                             NN, 256, 128);
  }
  prop_half<128, 1><<<gP, 256, 0, stream>>>(Xh, rp, col, dinv, b2, g2, be2, m2, v2,
                                            PA, NN);
  // ---- layer 3: GEMM3(*dinv) -> Xh[64], prop(64,+b3,BN3,ReLU) -> H[64] ----
  {
    dim3 g(gM, 1);
    mfma_gemm<64, 1><<<g, 256, 0, stream>>>(PA, Wt3h, Wt3l, nullptr, nullptr, nullptr,
                                            nullptr, nullptr, dinv, nullptr, Xh,
                                            NN, 128, 64);
  }
  prop_half<64, 1><<<gP, 256, 0, stream>>>(Xh, rp, col, dinv, b3, g3, be3, m3, v3,
                                           H, NN);
  // ---- layer 4: GEMM4(*dinv) -> F1 f32 (N=6), final prop (+b4) ----
  {
    dim3 g(gM, 1);
    mfma_gemm<16, 2><<<g, 256, 0, stream>>>(H, Wt4h, Wt4l, nullptr, nullptr, nullptr,
                                            nullptr, nullptr, dinv, F1, nullptr,
                                            NN, 64, 6);
  }
  prop_small<<<(NN + 31) / 32, 256, 0, stream>>>(F1, rp, col, dinv, b4, out, NN);
}

// Round 16
// 231.589 us; speedup vs baseline: 1.1078x; 1.0258x over previous
//
#include <hip/hip_runtime.h>
#include <hip/hip_bf16.h>
#include <hip/hip_fp16.h>

#define EPS 1e-5f

constexpr int NN = 50000;   // nodes
constexpr int NE = 800000;  // edges

typedef __attribute__((ext_vector_type(8))) _Float16 f16x8;
typedef __attribute__((ext_vector_type(4))) float f32x4;

// ---------------- utility ----------------
__global__ void memset_i32(int* p, int n) {
  int i = blockIdx.x * blockDim.x + threadIdx.x;
  if (i < n) p[i] = 0;
}

// ---------------- degree + slot capture ----------------
// pos8[i] = this edge's arrival rank at its dst (max deg ~40 << 255)
__global__ void deg_pos(const int* __restrict__ dst, int* __restrict__ degi,
                        unsigned char* __restrict__ pos8, int n) {
  int i = blockIdx.x * blockDim.x + threadIdx.x;
  if (i < n) pos8[i] = (unsigned char)atomicAdd(&degi[dst[i]], 1);
}

// ---------------- scan (row_ptr build) ----------------
__global__ __launch_bounds__(1024) void scan1(const int* __restrict__ cnt,
                                              int* __restrict__ incl,
                                              int* __restrict__ bsum, int n) {
  __shared__ int s[1024];
  int tid = threadIdx.x;
  int i = blockIdx.x * 1024 + tid;
  int v = (i < n) ? cnt[i] : 0;
  s[tid] = v;
  __syncthreads();
  for (int off = 1; off < 1024; off <<= 1) {
    int t = (tid >= off) ? s[tid - off] : 0;
    __syncthreads();
    s[tid] += t;
    __syncthreads();
  }
  if (i < n) incl[i] = s[tid];
  if (tid == 1023) bsum[blockIdx.x] = s[1023];
}

__global__ void scan2(int* __restrict__ bsum, int nb) {
  int lane = threadIdx.x;  // single wave of 64
  int v = (lane < nb) ? bsum[lane] : 0;
  int orig = v;
  for (int off = 1; off < 64; off <<= 1) {
    int t = __shfl_up(v, off, 64);
    if (lane >= off) v += t;
  }
  if (lane < nb) bsum[lane] = v - orig;  // exclusive block offset
}

// scan3 + fused dinv compute
__global__ __launch_bounds__(1024) void scan3(const int* __restrict__ cnt,
                                              const int* __restrict__ incl,
                                              const int* __restrict__ bsum,
                                              int* __restrict__ rp,
                                              float* __restrict__ dinv, int n) {
  int tid = threadIdx.x;
  int i = blockIdx.x * 1024 + tid;
  if (i < n) {
    rp[i + 1] = incl[i] + bsum[blockIdx.x];
    dinv[i] = rsqrtf((float)(cnt[i] + 1));  // +1 self loop
  }
  if (i == 0) rp[0] = 0;
}

// atomic-free fill: position known from deg_pos capture
__global__ void fill_kernel(const int* __restrict__ src, const int* __restrict__ dst,
                            const int* __restrict__ rp,
                            const unsigned char* __restrict__ pos8,
                            unsigned short* __restrict__ col, int n) {
  int i = blockIdx.x * blockDim.x + threadIdx.x;
  if (i < n) col[rp[dst[i]] + pos8[i]] = (unsigned short)src[i];
}

// ---------------- fused: weight transpose (single fp16 plane) + x prescale->fp16 ----
// r15 proved fp16 activations add zero extra error; weight fp16 rounding adds
// ~2^-11 relative (predicted absmax ~1e-3 < 2.19e-3 threshold).
__device__ __forceinline__ void wsplit_one(const float* W, __half* th,
                                           int j, int K, int N) {
  int k = j / N, n = j - k * N;
  th[(size_t)n * K + k] = __float2half(W[j]);
}

__global__ void wsplit_scale(const float* __restrict__ W1, __half* t1,
                             const float* __restrict__ W2, __half* t2,
                             const float* __restrict__ W3, __half* t3,
                             const float* __restrict__ W4, __half* t4,
                             const float* __restrict__ x, const float* __restrict__ dinv,
                             __half* __restrict__ Xh) {
  int i = blockIdx.x * blockDim.x + threadIdx.x;
  if (i < 32768) { wsplit_one(W1, t1, i, 128, 256); return; }
  if (i < 65536) { wsplit_one(W2, t2, i - 32768, 256, 128); return; }
  if (i < 73728) { wsplit_one(W3, t3, i - 65536, 128, 64); return; }
  if (i < 74112) { wsplit_one(W4, t4, i - 73728, 64, 6); return; }
  int k = i - 74112;  // float4 index over x[NN][128]
  if (k >= NN * 32) return;
  int v = k >> 5, f = (k & 31) * 4;
  float4 t = ((const float4*)x)[k];
  float s = dinv[v];
  __half2* d = (__half2*)(Xh + (size_t)v * 128 + f);
  d[0] = __floats2half2_rn(t.x * s, t.y * s);
  d[1] = __floats2half2_rn(t.z * s, t.w * s);
}

// ---------------- propagation (pull over CSR), fp16 gather planes, D=8 ----------------
// One wave per node; input rows fp16, prescaled by dinv[src]. 8 gathers in
// flight per wave; f32 accumulate. D=8 @ 8 waves/SIMD is the proven operating
// point (D=16 under launch_bounds(256,8) spills: r12, WRITE 25->176MB).
// EPI 0 = *dinv[v]; 1 = *dinv[v]+bias+BN+ReLU. Output: single fp16 plane.
template <int F, int EPI>
__global__ __launch_bounds__(256, 8) void prop_half(
    const __half* __restrict__ in, const int* __restrict__ rp,
    const unsigned short* __restrict__ col,
    const float* __restrict__ dinv, const float* __restrict__ bias,
    const float* __restrict__ gam, const float* __restrict__ bet,
    const float* __restrict__ mean, const float* __restrict__ var,
    __half* __restrict__ out_h, int nnodes) {
  int tid = threadIdx.x;
  int wid = tid >> 6, lane = tid & 63;
  constexpr int VEC = F / 64;  // 2 for F=128, 1 for F=64
  int v = blockIdx.x * 4 + wid;
  if (v >= nnodes) return;
  int e0 = rp[v], e1 = rp[v + 1];
  float acc[VEC];
  if constexpr (VEC == 2) {
    float2 f = __half22float2(*(const __half2*)(in + (size_t)v * F + lane * 2));
    acc[0] = f.x; acc[1] = f.y;
  } else {
    acc[0] = __half2float(in[(size_t)v * F + lane]);
  }
  int e1m1 = e1 - 1;
  constexpr int D = 8;
  for (int e = e0; e < e1; e += D) {
    bool full = (e + D <= e1);
    int ss[D];
    if (full) {
#pragma unroll
      for (int u = 0; u < D; u++) ss[u] = col[e + u];
      if constexpr (VEC == 2) {
        __half2 hv[D];
#pragma unroll
        for (int u = 0; u < D; u++)
          hv[u] = *(const __half2*)(in + (size_t)ss[u] * F + lane * 2);
#pragma unroll
        for (int u = 0; u < D; u++) {
          float2 f = __half22float2(hv[u]);
          acc[0] += f.x;
          acc[1] += f.y;
        }
      } else {
        __half hv[D];
#pragma unroll
        for (int u = 0; u < D; u++) hv[u] = in[(size_t)ss[u] * F + lane];
#pragma unroll
        for (int u = 0; u < D; u++) acc[0] += __half2float(hv[u]);
      }
    } else {
      float w[D];
#pragma unroll
      for (int u = 0; u < D; u++) {
        int ei = e + u;
        ss[u] = col[ei < e1m1 ? ei : e1m1];
        w[u] = (ei < e1) ? 1.f : 0.f;
      }
      if constexpr (VEC == 2) {
        __half2 hv[D];
#pragma unroll
        for (int u = 0; u < D; u++)
          hv[u] = *(const __half2*)(in + (size_t)ss[u] * F + lane * 2);
#pragma unroll
        for (int u = 0; u < D; u++) {
          float2 f = __half22float2(hv[u]);
          acc[0] = fmaf(f.x, w[u], acc[0]);
          acc[1] = fmaf(f.y, w[u], acc[1]);
        }
      } else {
        __half hv[D];
#pragma unroll
        for (int u = 0; u < D; u++) hv[u] = in[(size_t)ss[u] * F + lane];
#pragma unroll
        for (int u = 0; u < D; u++) acc[0] = fmaf(__half2float(hv[u]), w[u], acc[0]);
      }
    }
  }
  float dv = dinv[v];
  float t0;
  {
    int f = lane * VEC;
    t0 = acc[0] * dv;
    if constexpr (EPI >= 1) {
      t0 += bias[f];
      t0 = (t0 - mean[f]) * rsqrtf(var[f] + EPS) * gam[f] + bet[f];
      t0 = fmaxf(t0, 0.f);
    }
  }
  if constexpr (VEC == 2) {
    int f = lane * 2 + 1;
    float t1 = acc[1] * dv;
    if constexpr (EPI >= 1) {
      t1 += bias[f];
      t1 = (t1 - mean[f]) * rsqrtf(var[f] + EPS) * gam[f] + bet[f];
      t1 = fmaxf(t1, 0.f);
    }
    *(__half2*)(out_h + (size_t)v * F + lane * 2) = __floats2half2_rn(t0, t1);
  } else {
    out_h[(size_t)v * F + lane] = __float2half(t0);
  }
}

// ---------------- final prop (F=6), f32 input ----------------
__global__ __launch_bounds__(256, 8) void prop_small(
    const float* __restrict__ in, const int* __restrict__ rp,
    const unsigned short* __restrict__ col,
    const float* __restrict__ dinv, const float* __restrict__ bias,
    float* __restrict__ out, int nnodes) {
  constexpr int F = 6;
  int tid = threadIdx.x;
  int wid = tid >> 6, lane = tid & 63;
  int g = lane >> 3, f = lane & 7;
  int v = (blockIdx.x * 4 + wid) * 8 + g;
  if (v >= nnodes || f >= F) return;
  int e0 = rp[v], e1 = rp[v + 1];
  float acc = in[(size_t)v * F + f];
  int e1m1 = e1 - 1;
  constexpr int D = 8;
  for (int e = e0; e < e1; e += D) {
    int ss[D];
    float w[D];
#pragma unroll
    for (int u = 0; u < D; u++) {
      int ei = e + u;
      ss[u] = col[ei < e1m1 ? ei : e1m1];
      w[u] = (ei < e1) ? 1.0f : 0.0f;
    }
#pragma unroll
    for (int u = 0; u < D; u++) acc = fmaf(in[(size_t)ss[u] * F + f], w[u], acc);
  }
  out[(size_t)v * F + f] = acc * dinv[v] + bias[f];
}

// ---------------- MFMA GEMM (fp16 single-pass), 128xBN tile, 4 waves ----------------
// A single fp16 plane [M][K]; B single fp16 transposed plane [N][K].
// 1 MFMA pass per (m,n) quadrant (was 2 in r15, 3 in bf16 split-3).
// EPI 0: +bias, BN, ReLU -> fp16 plane. EPI 1: *dinv[row] -> fp16 plane.
// EPI 2: *dinv[row] -> f32 linear (final small layer).
template <int BN, int EPI>
__global__ __launch_bounds__(256, 4) void mfma_gemm(
    const __half* __restrict__ A, const __half* __restrict__ B,
    const float* __restrict__ bias, const float* __restrict__ gam,
    const float* __restrict__ bet, const float* __restrict__ mean,
    const float* __restrict__ var, const float* __restrict__ dinv,
    float* __restrict__ Cf, __half* __restrict__ Ch,
    int M, int K, int N) {
  constexpr int BM = 128, BK = 32, NB = BN / 16;
  // +8 f16 pad (16 B): row stride 80 B spreads b128 frag reads across banks
  __shared__ __half Ah[BM][BK + 8];
  __shared__ __half Bs[BN][BK + 8];
  int tid = threadIdx.x;
  int wid = tid >> 6, lane = tid & 63;
  int lr = lane & 15, lg = lane >> 4;
  int bm = blockIdx.x * BM, bn = blockIdx.y * BN;
  f32x4 acc[2][NB] = {};
  for (int k0 = 0; k0 < K; k0 += BK) {
#pragma unroll
    for (int c = 0; c < 2; c++) {  // A tile: 128 rows x 32 f16, 16B chunks
      int idx = tid + c * 256;
      int r = idx >> 2, s = idx & 3;
      int rg = bm + r;
      uint4 va = {0, 0, 0, 0};
      if (rg < M) va = *reinterpret_cast<const uint4*>(A + (size_t)rg * K + k0 + s * 8);
      *reinterpret_cast<uint4*>(&Ah[r][s * 8]) = va;
    }
#pragma unroll
    for (int c = 0; c < (BN * 4 + 255) / 256; c++) {  // B tile: BN rows x 32 f16
      int idx = tid + c * 256;
      if (idx < BN * 4) {
        int r = idx >> 2, s = idx & 3;
        int rg = bn + r;
        uint4 vb = {0, 0, 0, 0};
        if (rg < N) vb = *reinterpret_cast<const uint4*>(B + (size_t)rg * K + k0 + s * 8);
        *reinterpret_cast<uint4*>(&Bs[r][s * 8]) = vb;
      }
    }
    __syncthreads();
    int ar = wid * 32 + lr;
    f16x8 a0 = *reinterpret_cast<const f16x8*>(&Ah[ar][lg * 8]);
    f16x8 a1 = *reinterpret_cast<const f16x8*>(&Ah[ar + 16][lg * 8]);
#pragma unroll
    for (int n = 0; n < NB; n++) {
      f16x8 b = *reinterpret_cast<const f16x8*>(&Bs[n * 16 + lr][lg * 8]);
      acc[0][n] = __builtin_amdgcn_mfma_f32_16x16x32_f16(a0, b, acc[0][n], 0, 0, 0);
      acc[1][n] = __builtin_amdgcn_mfma_f32_16x16x32_f16(a1, b, acc[1][n], 0, 0, 0);
    }
    __syncthreads();
  }
  // epilogue: C/D layout col=lane&15, row=(lane>>4)*4+reg (m89-verified)
#pragma unroll
  for (int m = 0; m < 2; m++) {
    int row0 = bm + wid * 32 + m * 16 + lg * 4;
#pragma unroll
    for (int n = 0; n < NB; n++) {
      int colg = bn + n * 16 + lr;
#pragma unroll
      for (int r = 0; r < 4; r++) {
        int row = row0 + r;
        if (row >= M || colg >= N) continue;
        float t = acc[m][n][r];
        if constexpr (EPI == 0) {
          t += bias[colg];
          t = (t - mean[colg]) * rsqrtf(var[colg] + EPS) * gam[colg] + bet[colg];
          t = fmaxf(t, 0.f);
          Ch[(size_t)row * N + colg] = __float2half(t);
        } else if constexpr (EPI == 1) {
          Ch[(size_t)row * N + colg] = __float2half(t * dinv[row]);
        } else {
          Cf[(size_t)row * N + colg] = t * dinv[row];
        }
      }
    }
  }
}

// ---------------- launch ----------------
extern "C" void kernel_launch(void* const* d_in, const int* in_sizes, int n_in,
                              void* d_out, int out_size, void* d_ws, size_t ws_size,
                              hipStream_t stream) {
  const float* x = (const float*)d_in[0];
  const int* ei = (const int*)d_in[1];
  const int* esrc = ei;
  const int* edst = ei + NE;
  const float* W1 = (const float*)d_in[2];  const float* b1 = (const float*)d_in[3];
  const float* g1 = (const float*)d_in[4];  const float* be1 = (const float*)d_in[5];
  const float* m1 = (const float*)d_in[6];  const float* v1 = (const float*)d_in[7];
  const float* W2 = (const float*)d_in[8];  const float* b2 = (const float*)d_in[9];
  const float* g2 = (const float*)d_in[10]; const float* be2 = (const float*)d_in[11];
  const float* m2 = (const float*)d_in[12]; const float* v2 = (const float*)d_in[13];
  const float* W3 = (const float*)d_in[14]; const float* b3 = (const float*)d_in[15];
  const float* g3 = (const float*)d_in[16]; const float* be3 = (const float*)d_in[17];
  const float* m3 = (const float*)d_in[18]; const float* v3 = (const float*)d_in[19];
  const float* W4 = (const float*)d_in[20]; const float* b4 = (const float*)d_in[21];
  float* out = (float*)d_out;

  // workspace layout
  char* base = (char*)d_ws;
  size_t off = 0;
  auto alloc = [&](size_t bytes) {
    void* p = base + off;
    off = (off + bytes + 255) & ~(size_t)255;
    return p;
  };
  __half* Xh = (__half*)alloc((size_t)NN * 128 * 2);   // fp16 gather plane (<=128 cols)
  __half* PA = (__half*)alloc((size_t)NN * 128 * 2);   // fp16 GEMM-A plane (<=128 cols)
  __half* H  = (__half*)alloc((size_t)NN * 256 * 2);   // fp16 wide plane (<=256 cols)
  float* F1 = (float*)alloc((size_t)NN * 6 * 4);       // f32 pre-final activations
  __half* Wt1 = (__half*)alloc(128 * 256 * 2);
  __half* Wt2 = (__half*)alloc(256 * 128 * 2);
  __half* Wt3 = (__half*)alloc(128 * 64 * 2);
  __half* Wt4 = (__half*)alloc(64 * 6 * 2);
  int* degi = (int*)alloc((size_t)NN * 4);
  float* dinv = (float*)alloc((size_t)NN * 4);
  int* rp = (int*)alloc((size_t)(NN + 1) * 4);
  int* incl = (int*)alloc((size_t)NN * 4);
  int* bsum = (int*)alloc(64 * 4);
  unsigned short* col = (unsigned short*)alloc((size_t)NE * 2);
  unsigned char* pos8 = (unsigned char*)alloc((size_t)NE);

  const int nBlkN = (NN + 255) / 256;
  const int nBlkE = (NE + 255) / 256;
  const int nBlkScan = (NN + 1023) / 1024;  // 49
  const int gM = (NN + 127) / 128;          // 391
  const int gP = (NN + 3) / 4;              // 12500

  // degree (+slot capture) + CSR (atomic-free fill)
  memset_i32<<<nBlkN, 256, 0, stream>>>(degi, NN);
  deg_pos<<<nBlkE, 256, 0, stream>>>(edst, degi, pos8, NE);
  scan1<<<nBlkScan, 1024, 0, stream>>>(degi, incl, bsum, NN);
  scan2<<<1, 64, 0, stream>>>(bsum, nBlkScan);
  scan3<<<nBlkScan, 1024, 0, stream>>>(degi, incl, bsum, rp, dinv, NN);
  fill_kernel<<<nBlkE, 256, 0, stream>>>(esrc, edst, rp, pos8, col, NE);

  // fused weight transpose (fp16) + x prescale->fp16
  wsplit_scale<<<(74112 + NN * 32 + 255) / 256, 256, 0, stream>>>(
      W1, Wt1, W2, Wt2, W3, Wt3, W4, Wt4, x, dinv, Xh);

  // ---- layer 1: prop(128) -> PA, GEMM1(+b1,BN1,ReLU) -> H[256] ----
  prop_half<128, 0><<<gP, 256, 0, stream>>>(Xh, rp, col, dinv, nullptr, nullptr, nullptr,
                                            nullptr, nullptr, PA, NN);
  {
    dim3 g(gM, 2);
    mfma_gemm<128, 0><<<g, 256, 0, stream>>>(PA, Wt1, b1, g1, be1, m1, v1,
                                             nullptr, nullptr, H, NN, 128, 256);
  }
  // ---- layer 2: GEMM2(*dinv) -> Xh[128], prop(128,+b2,BN2,ReLU) -> PA ----
  {
    dim3 g(gM, 1);
    mfma_gemm<128, 1><<<g, 256, 0, stream>>>(H, Wt2, nullptr, nullptr, nullptr,
                                             nullptr, nullptr, dinv, nullptr, Xh,
                                             NN, 256, 128);
  }
  prop_half<128, 1><<<gP, 256, 0, stream>>>(Xh, rp, col, dinv, b2, g2, be2, m2, v2,
                                            PA, NN);
  // ---- layer 3: GEMM3(*dinv) -> Xh[64], prop(64,+b3,BN3,ReLU) -> H[64] ----
  {
    dim3 g(gM, 1);
    mfma_gemm<64, 1><<<g, 256, 0, stream>>>(PA, Wt3, nullptr, nullptr, nullptr,
                                            nullptr, nullptr, dinv, nullptr, Xh,
                                            NN, 128, 64);
  }
  prop_half<64, 1><<<gP, 256, 0, stream>>>(Xh, rp, col, dinv, b3, g3, be3, m3, v3,
                                           H, NN);
  // ---- layer 4: GEMM4(*dinv) -> F1 f32 (N=6), final prop (+b4) ----
  {
    dim3 g(gM, 1);
    mfma_gemm<16, 2><<<g, 256, 0, stream>>>(H, Wt4, nullptr, nullptr, nullptr,
                                            nullptr, nullptr, dinv, F1, nullptr,
                                            NN, 64, 6);
  }
  prop_small<<<(NN + 31) / 32, 256, 0, stream>>>(F1, rp, col, dinv, b4, out, NN);
}

// Round 17
// 230.125 us; speedup vs baseline: 1.1149x; 1.0064x over previous
//
#include <hip/hip_runtime.h>
#include <hip/hip_bf16.h>
#include <hip/hip_fp16.h>

#define EPS 1e-5f

constexpr int NN = 50000;   // nodes
constexpr int NE = 800000;  // edges
constexpr int NBLK_SCAN = (NN + 1023) / 1024;  // 49

typedef __attribute__((ext_vector_type(8))) _Float16 f16x8;
typedef __attribute__((ext_vector_type(4))) float f32x4;

// ---------------- utility ----------------
__global__ void memset_i32(int* p, int n) {
  int i = blockIdx.x * blockDim.x + threadIdx.x;
  if (i < n) p[i] = 0;
}

// ---------------- degree + slot capture ----------------
// pos8[i] = this edge's arrival rank at its dst (max deg ~40 << 255)
__global__ void deg_pos(const int* __restrict__ dst, int* __restrict__ degi,
                        unsigned char* __restrict__ pos8, int n) {
  int i = blockIdx.x * blockDim.x + threadIdx.x;
  if (i < n) pos8[i] = (unsigned char)atomicAdd(&degi[dst[i]], 1);
}

// ---------------- scan (row_ptr build) ----------------
__global__ __launch_bounds__(1024) void scan1(const int* __restrict__ cnt,
                                              int* __restrict__ incl,
                                              int* __restrict__ bsum, int n) {
  __shared__ int s[1024];
  int tid = threadIdx.x;
  int i = blockIdx.x * 1024 + tid;
  int v = (i < n) ? cnt[i] : 0;
  s[tid] = v;
  __syncthreads();
  for (int off = 1; off < 1024; off <<= 1) {
    int t = (tid >= off) ? s[tid - off] : 0;
    __syncthreads();
    s[tid] += t;
    __syncthreads();
  }
  if (i < n) incl[i] = s[tid];
  if (tid == 1023) bsum[blockIdx.x] = s[1023];
}

// scan3 with scan2 fused: first wave of every block redundantly scans the 49
// block sums (cheap) -> one fewer launch + dependency bubble.
__global__ __launch_bounds__(1024) void scan3(const int* __restrict__ cnt,
                                              const int* __restrict__ incl,
                                              const int* __restrict__ bsum,
                                              int* __restrict__ rp,
                                              float* __restrict__ dinv, int n) {
  __shared__ int boff_s;
  int tid = threadIdx.x;
  if (tid < 64) {  // wave 0: exclusive-scan bsum[0..NBLK_SCAN) and pick ours
    int lane = tid;
    int v = (lane < NBLK_SCAN) ? bsum[lane] : 0;
    int orig = v;
    for (int off = 1; off < 64; off <<= 1) {
      int t = __shfl_up(v, off, 64);
      if (lane >= off) v += t;
    }
    // exclusive offset for block blockIdx.x
    if (lane == blockIdx.x) boff_s = v - orig;
  }
  __syncthreads();
  int boff = boff_s;
  int i = blockIdx.x * 1024 + tid;
  if (i < n) {
    rp[i + 1] = incl[i] + boff;
    dinv[i] = rsqrtf((float)(cnt[i] + 1));  // +1 self loop
  }
  if (i == 0) rp[0] = 0;
}

// atomic-free fill: position known from deg_pos capture
__global__ void fill_kernel(const int* __restrict__ src, const int* __restrict__ dst,
                            const int* __restrict__ rp,
                            const unsigned char* __restrict__ pos8,
                            unsigned short* __restrict__ col, int n) {
  int i = blockIdx.x * blockDim.x + threadIdx.x;
  if (i < n) col[rp[dst[i]] + pos8[i]] = (unsigned short)src[i];
}

// ---------------- fused: weight transpose (single fp16 plane) + x prescale->fp16 ----
__device__ __forceinline__ void wsplit_one(const float* W, __half* th,
                                           int j, int K, int N) {
  int k = j / N, n = j - k * N;
  th[(size_t)n * K + k] = __float2half(W[j]);
}

__global__ void wsplit_scale(const float* __restrict__ W1, __half* t1,
                             const float* __restrict__ W2, __half* t2,
                             const float* __restrict__ W3, __half* t3,
                             const float* __restrict__ W4, __half* t4,
                             const float* __restrict__ x, const float* __restrict__ dinv,
                             __half* __restrict__ Xh) {
  int i = blockIdx.x * blockDim.x + threadIdx.x;
  if (i < 32768) { wsplit_one(W1, t1, i, 128, 256); return; }
  if (i < 65536) { wsplit_one(W2, t2, i - 32768, 256, 128); return; }
  if (i < 73728) { wsplit_one(W3, t3, i - 65536, 128, 64); return; }
  if (i < 74112) { wsplit_one(W4, t4, i - 73728, 64, 6); return; }
  int k = i - 74112;  // float4 index over x[NN][128]
  if (k >= NN * 32) return;
  int v = k >> 5, f = (k & 31) * 4;
  float4 t = ((const float4*)x)[k];
  float s = dinv[v];
  __half2* d = (__half2*)(Xh + (size_t)v * 128 + f);
  d[0] = __floats2half2_rn(t.x * s, t.y * s);
  d[1] = __floats2half2_rn(t.z * s, t.w * s);
}

// ---------------- propagation (pull over CSR), fp16 gather planes, D=8 ----------------
// One wave per node; input rows fp16, prescaled by dinv[src]. 8 gathers in
// flight per wave; f32 accumulate. D=8 @ 8 waves/SIMD is the proven operating
// point (D=16 under launch_bounds(256,8) spills: r12, WRITE 25->176MB).
// EPI 0 = *dinv[v]; 1 = *dinv[v]+bias+BN+ReLU. Output: single fp16 plane.
template <int F, int EPI>
__global__ __launch_bounds__(256, 8) void prop_half(
    const __half* __restrict__ in, const int* __restrict__ rp,
    const unsigned short* __restrict__ col,
    const float* __restrict__ dinv, const float* __restrict__ bias,
    const float* __restrict__ gam, const float* __restrict__ bet,
    const float* __restrict__ mean, const float* __restrict__ var,
    __half* __restrict__ out_h, int nnodes) {
  int tid = threadIdx.x;
  int wid = tid >> 6, lane = tid & 63;
  constexpr int VEC = F / 64;  // 2 for F=128, 1 for F=64
  int v = blockIdx.x * 4 + wid;
  if (v >= nnodes) return;
  int e0 = rp[v], e1 = rp[v + 1];
  float acc[VEC];
  if constexpr (VEC == 2) {
    float2 f = __half22float2(*(const __half2*)(in + (size_t)v * F + lane * 2));
    acc[0] = f.x; acc[1] = f.y;
  } else {
    acc[0] = __half2float(in[(size_t)v * F + lane]);
  }
  int e1m1 = e1 - 1;
  constexpr int D = 8;
  for (int e = e0; e < e1; e += D) {
    bool full = (e + D <= e1);
    int ss[D];
    if (full) {
#pragma unroll
      for (int u = 0; u < D; u++) ss[u] = col[e + u];
      if constexpr (VEC == 2) {
        __half2 hv[D];
#pragma unroll
        for (int u = 0; u < D; u++)
          hv[u] = *(const __half2*)(in + (size_t)ss[u] * F + lane * 2);
#pragma unroll
        for (int u = 0; u < D; u++) {
          float2 f = __half22float2(hv[u]);
          acc[0] += f.x;
          acc[1] += f.y;
        }
      } else {
        __half hv[D];
#pragma unroll
        for (int u = 0; u < D; u++) hv[u] = in[(size_t)ss[u] * F + lane];
#pragma unroll
        for (int u = 0; u < D; u++) acc[0] += __half2float(hv[u]);
      }
    } else {
      float w[D];
#pragma unroll
      for (int u = 0; u < D; u++) {
        int ei = e + u;
        ss[u] = col[ei < e1m1 ? ei : e1m1];
        w[u] = (ei < e1) ? 1.f : 0.f;
      }
      if constexpr (VEC == 2) {
        __half2 hv[D];
#pragma unroll
        for (int u = 0; u < D; u++)
          hv[u] = *(const __half2*)(in + (size_t)ss[u] * F + lane * 2);
#pragma unroll
        for (int u = 0; u < D; u++) {
          float2 f = __half22float2(hv[u]);
          acc[0] = fmaf(f.x, w[u], acc[0]);
          acc[1] = fmaf(f.y, w[u], acc[1]);
        }
      } else {
        __half hv[D];
#pragma unroll
        for (int u = 0; u < D; u++) hv[u] = in[(size_t)ss[u] * F + lane];
#pragma unroll
        for (int u = 0; u < D; u++) acc[0] = fmaf(__half2float(hv[u]), w[u], acc[0]);
      }
    }
  }
  float dv = dinv[v];
  float t0;
  {
    int f = lane * VEC;
    t0 = acc[0] * dv;
    if constexpr (EPI >= 1) {
      t0 += bias[f];
      t0 = (t0 - mean[f]) * rsqrtf(var[f] + EPS) * gam[f] + bet[f];
      t0 = fmaxf(t0, 0.f);
    }
  }
  if constexpr (VEC == 2) {
    int f = lane * 2 + 1;
    float t1 = acc[1] * dv;
    if constexpr (EPI >= 1) {
      t1 += bias[f];
      t1 = (t1 - mean[f]) * rsqrtf(var[f] + EPS) * gam[f] + bet[f];
      t1 = fmaxf(t1, 0.f);
    }
    *(__half2*)(out_h + (size_t)v * F + lane * 2) = __floats2half2_rn(t0, t1);
  } else {
    out_h[(size_t)v * F + lane] = __float2half(t0);
  }
}

// ---------------- final prop (F=6), f32 input ----------------
__global__ __launch_bounds__(256, 8) void prop_small(
    const float* __restrict__ in, const int* __restrict__ rp,
    const unsigned short* __restrict__ col,
    const float* __restrict__ dinv, const float* __restrict__ bias,
    float* __restrict__ out, int nnodes) {
  constexpr int F = 6;
  int tid = threadIdx.x;
  int wid = tid >> 6, lane = tid & 63;
  int g = lane >> 3, f = lane & 7;
  int v = (blockIdx.x * 4 + wid) * 8 + g;
  if (v >= nnodes || f >= F) return;
  int e0 = rp[v], e1 = rp[v + 1];
  float acc = in[(size_t)v * F + f];
  int e1m1 = e1 - 1;
  constexpr int D = 8;
  for (int e = e0; e < e1; e += D) {
    int ss[D];
    float w[D];
#pragma unroll
    for (int u = 0; u < D; u++) {
      int ei = e + u;
      ss[u] = col[ei < e1m1 ? ei : e1m1];
      w[u] = (ei < e1) ? 1.0f : 0.0f;
    }
#pragma unroll
    for (int u = 0; u < D; u++) acc = fmaf(in[(size_t)ss[u] * F + f], w[u], acc);
  }
  out[(size_t)v * F + f] = acc * dinv[v] + bias[f];
}

// ---------------- MFMA GEMM (fp16 single-pass), 128xBN tile, 4 waves ----------------
// A single fp16 plane [M][K]; B single fp16 transposed plane [N][K].
// EPI 0: +bias, BN, ReLU -> fp16 plane. EPI 1: *dinv[row] -> fp16 plane.
// EPI 2: *dinv[row] -> f32 linear (final small layer).
template <int BN, int EPI>
__global__ __launch_bounds__(256, 4) void mfma_gemm(
    const __half* __restrict__ A, const __half* __restrict__ B,
    const float* __restrict__ bias, const float* __restrict__ gam,
    const float* __restrict__ bet, const float* __restrict__ mean,
    const float* __restrict__ var, const float* __restrict__ dinv,
    float* __restrict__ Cf, __half* __restrict__ Ch,
    int M, int K, int N) {
  constexpr int BM = 128, BK = 32, NB = BN / 16;
  // +8 f16 pad (16 B): row stride 80 B spreads b128 frag reads across banks
  __shared__ __half Ah[BM][BK + 8];
  __shared__ __half Bs[BN][BK + 8];
  int tid = threadIdx.x;
  int wid = tid >> 6, lane = tid & 63;
  int lr = lane & 15, lg = lane >> 4;
  int bm = blockIdx.x * BM, bn = blockIdx.y * BN;
  f32x4 acc[2][NB] = {};
  for (int k0 = 0; k0 < K; k0 += BK) {
#pragma unroll
    for (int c = 0; c < 2; c++) {  // A tile: 128 rows x 32 f16, 16B chunks
      int idx = tid + c * 256;
      int r = idx >> 2, s = idx & 3;
      int rg = bm + r;
      uint4 va = {0, 0, 0, 0};
      if (rg < M) va = *reinterpret_cast<const uint4*>(A + (size_t)rg * K + k0 + s * 8);
      *reinterpret_cast<uint4*>(&Ah[r][s * 8]) = va;
    }
#pragma unroll
    for (int c = 0; c < (BN * 4 + 255) / 256; c++) {  // B tile: BN rows x 32 f16
      int idx = tid + c * 256;
      if (idx < BN * 4) {
        int r = idx >> 2, s = idx & 3;
        int rg = bn + r;
        uint4 vb = {0, 0, 0, 0};
        if (rg < N) vb = *reinterpret_cast<const uint4*>(B + (size_t)rg * K + k0 + s * 8);
        *reinterpret_cast<uint4*>(&Bs[r][s * 8]) = vb;
      }
    }
    __syncthreads();
    int ar = wid * 32 + lr;
    f16x8 a0 = *reinterpret_cast<const f16x8*>(&Ah[ar][lg * 8]);
    f16x8 a1 = *reinterpret_cast<const f16x8*>(&Ah[ar + 16][lg * 8]);
#pragma unroll
    for (int n = 0; n < NB; n++) {
      f16x8 b = *reinterpret_cast<const f16x8*>(&Bs[n * 16 + lr][lg * 8]);
      acc[0][n] = __builtin_amdgcn_mfma_f32_16x16x32_f16(a0, b, acc[0][n], 0, 0, 0);
      acc[1][n] = __builtin_amdgcn_mfma_f32_16x16x32_f16(a1, b, acc[1][n], 0, 0, 0);
    }
    __syncthreads();
  }
  // epilogue: C/D layout col=lane&15, row=(lane>>4)*4+reg (m89-verified)
#pragma unroll
  for (int m = 0; m < 2; m++) {
    int row0 = bm + wid * 32 + m * 16 + lg * 4;
#pragma unroll
    for (int n = 0; n < NB; n++) {
      int colg = bn + n * 16 + lr;
#pragma unroll
      for (int r = 0; r < 4; r++) {
        int row = row0 + r;
        if (row >= M || colg >= N) continue;
        float t = acc[m][n][r];
        if constexpr (EPI == 0) {
          t += bias[colg];
          t = (t - mean[colg]) * rsqrtf(var[colg] + EPS) * gam[colg] + bet[colg];
          t = fmaxf(t, 0.f);
          Ch[(size_t)row * N + colg] = __float2half(t);
        } else if constexpr (EPI == 1) {
          Ch[(size_t)row * N + colg] = __float2half(t * dinv[row]);
        } else {
          Cf[(size_t)row * N + colg] = t * dinv[row];
        }
      }
    }
  }
}

// ---------------- launch ----------------
extern "C" void kernel_launch(void* const* d_in, const int* in_sizes, int n_in,
                              void* d_out, int out_size, void* d_ws, size_t ws_size,
                              hipStream_t stream) {
  const float* x = (const float*)d_in[0];
  const int* ei = (const int*)d_in[1];
  const int* esrc = ei;
  const int* edst = ei + NE;
  const float* W1 = (const float*)d_in[2];  const float* b1 = (const float*)d_in[3];
  const float* g1 = (const float*)d_in[4];  const float* be1 = (const float*)d_in[5];
  const float* m1 = (const float*)d_in[6];  const float* v1 = (const float*)d_in[7];
  const float* W2 = (const float*)d_in[8];  const float* b2 = (const float*)d_in[9];
  const float* g2 = (const float*)d_in[10]; const float* be2 = (const float*)d_in[11];
  const float* m2 = (const float*)d_in[12]; const float* v2 = (const float*)d_in[13];
  const float* W3 = (const float*)d_in[14]; const float* b3 = (const float*)d_in[15];
  const float* g3 = (const float*)d_in[16]; const float* be3 = (const float*)d_in[17];
  const float* m3 = (const float*)d_in[18]; const float* v3 = (const float*)d_in[19];
  const float* W4 = (const float*)d_in[20]; const float* b4 = (const float*)d_in[21];
  float* out = (float*)d_out;

  // workspace layout
  char* base = (char*)d_ws;
  size_t off = 0;
  auto alloc = [&](size_t bytes) {
    void* p = base + off;
    off = (off + bytes + 255) & ~(size_t)255;
    return p;
  };
  __half* Xh = (__half*)alloc((size_t)NN * 128 * 2);   // fp16 gather plane (<=128 cols)
  __half* PA = (__half*)alloc((size_t)NN * 128 * 2);   // fp16 GEMM-A plane (<=128 cols)
  __half* H  = (__half*)alloc((size_t)NN * 256 * 2);   // fp16 wide plane (<=256 cols)
  float* F1 = (float*)alloc((size_t)NN * 6 * 4);       // f32 pre-final activations
  __half* Wt1 = (__half*)alloc(128 * 256 * 2);
  __half* Wt2 = (__half*)alloc(256 * 128 * 2);
  __half* Wt3 = (__half*)alloc(128 * 64 * 2);
  __half* Wt4 = (__half*)alloc(64 * 6 * 2);
  int* degi = (int*)alloc((size_t)NN * 4);
  float* dinv = (float*)alloc((size_t)NN * 4);
  int* rp = (int*)alloc((size_t)(NN + 1) * 4);
  int* incl = (int*)alloc((size_t)NN * 4);
  int* bsum = (int*)alloc(64 * 4);
  unsigned short* col = (unsigned short*)alloc((size_t)NE * 2);
  unsigned char* pos8 = (unsigned char*)alloc((size_t)NE);

  const int nBlkN = (NN + 255) / 256;
  const int nBlkE = (NE + 255) / 256;
  const int gM = (NN + 127) / 128;          // 391
  const int gP = (NN + 3) / 4;              // 12500

  // degree (+slot capture) + CSR (atomic-free fill; scan2 fused into scan3)
  memset_i32<<<nBlkN, 256, 0, stream>>>(degi, NN);
  deg_pos<<<nBlkE, 256, 0, stream>>>(edst, degi, pos8, NE);
  scan1<<<NBLK_SCAN, 1024, 0, stream>>>(degi, incl, bsum, NN);
  scan3<<<NBLK_SCAN, 1024, 0, stream>>>(degi, incl, bsum, rp, dinv, NN);
  fill_kernel<<<nBlkE, 256, 0, stream>>>(esrc, edst, rp, pos8, col, NE);

  // fused weight transpose (fp16) + x prescale->fp16
  wsplit_scale<<<(74112 + NN * 32 + 255) / 256, 256, 0, stream>>>(
      W1, Wt1, W2, Wt2, W3, Wt3, W4, Wt4, x, dinv, Xh);

  // ---- layer 1: prop(128) -> PA, GEMM1(+b1,BN1,ReLU) -> H[256] ----
  prop_half<128, 0><<<gP, 256, 0, stream>>>(Xh, rp, col, dinv, nullptr, nullptr, nullptr,
                                            nullptr, nullptr, PA, NN);
  {
    dim3 g(gM, 2);
    mfma_gemm<128, 0><<<g, 256, 0, stream>>>(PA, Wt1, b1, g1, be1, m1, v1,
                                             nullptr, nullptr, H, NN, 128, 256);
  }
  // ---- layer 2: GEMM2(*dinv) -> Xh[128], prop(128,+b2,BN2,ReLU) -> PA ----
  {
    dim3 g(gM, 1);
    mfma_gemm<128, 1><<<g, 256, 0, stream>>>(H, Wt2, nullptr, nullptr, nullptr,
                                             nullptr, nullptr, dinv, nullptr, Xh,
                                             NN, 256, 128);
  }
  prop_half<128, 1><<<gP, 256, 0, stream>>>(Xh, rp, col, dinv, b2, g2, be2, m2, v2,
                                            PA, NN);
  // ---- layer 3: GEMM3(*dinv) -> Xh[64], prop(64,+b3,BN3,ReLU) -> H[64] ----
  {
    dim3 g(gM, 1);
    mfma_gemm<64, 1><<<g, 256, 0, stream>>>(PA, Wt3, nullptr, nullptr, nullptr,
                                            nullptr, nullptr, dinv, nullptr, Xh,
                                            NN, 128, 64);
  }
  prop_half<64, 1><<<gP, 256, 0, stream>>>(Xh, rp, col, dinv, b3, g3, be3, m3, v3,
                                           H, NN);
  // ---- layer 4: GEMM4(*dinv) -> F1 f32 (N=6), final prop (+b4) ----
  {
    dim3 g(gM, 1);
    mfma_gemm<16, 2><<<g, 256, 0, stream>>>(H, Wt4, nullptr, nullptr, nullptr,
                                            nullptr, nullptr, dinv, F1, nullptr,
                                            NN, 64, 6);
  }
  prop_small<<<(NN + 31) / 32, 256, 0, stream>>>(F1, rp, col, dinv, b4, out, NN);
}